// Round 3
// baseline (500.069 us; speedup 1.0000x reference)
//
#include <hip/hip_runtime.h>
#include <cstdint>
#include <cstddef>

typedef float v4f __attribute__((ext_vector_type(4)));
typedef int   v4i __attribute__((ext_vector_type(4)));

// Problem constants (from reference): B=4, N=65536, K=16, D=8, OUT=8
namespace {
constexpr int Bn = 4;
constexpr int Nn = 65536;
constexpr int Kn = 16;
constexpr int NK = Nn * Kn;          // 1<<20
constexpr int TOTAL = Bn * NK;       // 1<<22 = 4,194,304
constexpr int QPB = NK / 4;          // quads per batch = 262144 = 1<<18
constexpr float COUNT_F = 4194304.0f;
constexpr float EPS = 1e-6f;
constexpr float SLOPE = 0.2f;
// out0 = (B,16,N,K) then out1 = (B,8,N,K), concatenated flat
constexpr long long OUT0_TOTAL = (long long)Bn * 16 * NK;  // 67,108,864
}

// ws layout (bytes):
//   [0, 416)            : stats — [0..7]=sum, [8..15]=sumsq, [16..95]=fused W, [96..103]=fused b
//   [1024, 1024+4MB)    : cpad  — coords padded to float4, B*N entries (sequential center reads)
//   [1024+4MB, +16MB)   : rec   — 64B/point combined record {x,y,z,_, f0..f7, pad4}
//                                 -> every neighbor gather touches EXACTLY ONE cacheline

// ---------------- prep: zero stats, pad coords, build combined records ----------------
__global__ __launch_bounds__(256) void prep_kernel(
    const float* __restrict__ coords,     // (B,N,3)
    const float* __restrict__ features,   // (B,8,N)
    float* __restrict__ stats,
    v4f* __restrict__ cpad,               // B*N
    v4f* __restrict__ rec)                // B*N*4 (64B per point)
{
    if (blockIdx.x == 0 && threadIdx.x < 16) stats[threadIdx.x] = 0.0f;
    int t = blockIdx.x * blockDim.x + threadIdx.x;   // 0 .. B*N-1
    if (t >= Bn * Nn) return;
    int b = t >> 16;             // N = 65536
    int n = t & (Nn - 1);
    const float* c = coords + (size_t)t * 3;
    v4f cv = {c[0], c[1], c[2], 0.0f};
    cpad[t] = cv;
    const float* fb = features + (size_t)b * 8 * Nn + n;
    v4f lo = {fb[0 * Nn], fb[1 * Nn], fb[2 * Nn], fb[3 * Nn]};
    v4f hi = {fb[4 * Nn], fb[5 * Nn], fb[6 * Nn], fb[7 * Nn]};
    v4f* rp = rec + ((size_t)t << 2);
    rp[0] = cv;
    rp[1] = lo;
    rp[2] = hi;
    // rp[3] left as padding (never read)
}

// ---------------- fallback stats init (no-prep path) ----------------
__global__ void init_kernel(float* __restrict__ stats) {
    if (threadIdx.x < 16) stats[threadIdx.x] = 0.0f;
}

// ---------------- pass 1: per-channel sum & sumsq of pre-BN y ----------------
// k-quad per thread; XCD-pinned batch mapping: blocks with ((blockIdx&7)>>1)==b
// only touch batch b's 1 MB cpad -> stays resident in that XCD's 4 MB L2.
template <bool PREP>
__global__ __launch_bounds__(256) void reduce_kernel(
    const v4i* __restrict__ nbr4,         // (B,N,K/4) int4
    const v4f* __restrict__ cpad,
    const float* __restrict__ coords,
    const float* __restrict__ conv_w,     // (8,10)
    const float* __restrict__ conv_b,     // (8,)
    float* __restrict__ stats)
{
    float w[80];
    #pragma unroll
    for (int i = 0; i < 80; i++) w[i] = conv_w[i];   // uniform -> scalar loads
    float bb[8];
    #pragma unroll
    for (int i = 0; i < 8; i++) bb[i] = conv_b[i];

    float s[8], sq[8];
    #pragma unroll
    for (int i = 0; i < 8; i++) { s[i] = 0.0f; sq[i] = 0.0f; }

    int xcd = blockIdx.x & 7;
    int b   = xcd >> 1;                                  // 2 XCDs per batch
    int wb  = ((blockIdx.x >> 3) << 1) | (xcd & 1);      // 0 .. gridDim/4-1
    int stride = (gridDim.x >> 2) * blockDim.x;          // threads per batch
    const float* cb = coords + (size_t)b * Nn * 3;

    for (int ql = wb * blockDim.x + threadIdx.x; ql < QPB; ql += stride) {
        v4i idx = __builtin_nontemporal_load(&nbr4[(b << 18) + ql]);
        int id[4] = {idx.x, idx.y, idx.z, idx.w};
        int n = ql >> 2;
        float ex, ey, ez;
        if (PREP) {
            v4f e = cpad[(b << 16) + n];
            ex = e.x; ey = e.y; ez = e.z;
        } else {
            ex = cb[n * 3]; ey = cb[n * 3 + 1]; ez = cb[n * 3 + 2];
        }
        #pragma unroll
        for (int k = 0; k < 4; k++) {
            float nx, ny, nz;
            if (PREP) {
                v4f q = cpad[(b << 16) + id[k]];
                nx = q.x; ny = q.y; nz = q.z;
            } else {
                nx = cb[id[k] * 3]; ny = cb[id[k] * 3 + 1]; nz = cb[id[k] * 3 + 2];
            }
            float rx = ex - nx, ry = ey - ny, rz = ez - nz;
            float dist = sqrtf(rx * rx + ry * ry + rz * rz);
            float rf[10] = {dist, rx, ry, rz, ex, ey, ez, nx, ny, nz};
            #pragma unroll
            for (int o = 0; o < 8; o++) {
                float y = bb[o];
                #pragma unroll
                for (int c = 0; c < 10; c++) y = fmaf(w[o * 10 + c], rf[c], y);
                s[o] += y;
                sq[o] = fmaf(y, y, sq[o]);
            }
        }
    }

    // wave-64 butterfly reduction of 16 values
    #pragma unroll
    for (int i = 0; i < 8; i++) {
        #pragma unroll
        for (int off = 32; off > 0; off >>= 1) {
            s[i]  += __shfl_xor(s[i], off, 64);
            sq[i] += __shfl_xor(sq[i], off, 64);
        }
    }
    __shared__ float ls[4][16];
    int lane = threadIdx.x & 63;
    int wv = threadIdx.x >> 6;
    if (lane == 0) {
        #pragma unroll
        for (int i = 0; i < 8; i++) { ls[wv][i] = s[i]; ls[wv][8 + i] = sq[i]; }
    }
    __syncthreads();
    if (threadIdx.x < 16) {
        float a = ls[0][threadIdx.x] + ls[1][threadIdx.x]
                + ls[2][threadIdx.x] + ls[3][threadIdx.x];
        atomicAdd(&stats[threadIdx.x], a);
    }
}

// ---------------- finalize: fold BN into conv weights ----------------
__global__ void finalize_kernel(
    const float* __restrict__ conv_w,
    const float* __restrict__ conv_b,
    const float* __restrict__ gamma,
    const float* __restrict__ beta,
    float* __restrict__ stats)
{
    int j = threadIdx.x;
    if (j >= 88) return;
    int o = (j < 80) ? (j / 10) : (j - 80);
    float mean = stats[o] * (1.0f / COUNT_F);
    float var = stats[8 + o] * (1.0f / COUNT_F) - mean * mean;
    var = fmaxf(var, 0.0f);
    float scale = gamma[o] * rsqrtf(var + EPS);
    if (j < 80) stats[16 + j] = conv_w[j] * scale;                    // fused W
    else        stats[96 + o] = (conv_b[o] - mean) * scale + beta[o]; // fused b
}

// ---------------- pass 2: recompute y (fused BN), gather nf, write outputs ----------------
// One k-quad per thread (grid exactly covers B*N*K/4). Each neighbor gather is
// ONE 64B cacheline (coords+features combined record). All 24 output channels
// are float4 nontemporal stores.
template <bool PREP>
__global__ __launch_bounds__(256) void output_kernel(
    const v4i* __restrict__ nbr4,
    const v4f* __restrict__ cpad,
    const float* __restrict__ coords,
    const v4f* __restrict__ rec,          // 64B/point combined record
    const float* __restrict__ features,   // raw (B,8,N) for fallback
    const float* __restrict__ stats,
    float* __restrict__ out)
{
    float w[80];
    #pragma unroll
    for (int i = 0; i < 80; i++) w[i] = stats[16 + i];  // uniform -> scalar loads
    float bb[8];
    #pragma unroll
    for (int i = 0; i < 8; i++) bb[i] = stats[96 + i];

    int xcd = blockIdx.x & 7;
    int b   = xcd >> 1;                                  // 2 XCDs per batch
    int wb  = ((blockIdx.x >> 3) << 1) | (xcd & 1);      // 0..1023
    int ql  = wb * blockDim.x + threadIdx.x;             // 0..262143 (quad id in batch)
    int n   = ql >> 2;

    v4i idx = __builtin_nontemporal_load(&nbr4[(b << 18) + ql]);
    int id[4] = {idx.x, idx.y, idx.z, idx.w};

    const float* cb = coords + (size_t)b * Nn * 3;
    float ex, ey, ez;
    if (PREP) {
        v4f e = cpad[(b << 16) + n];
        ex = e.x; ey = e.y; ez = e.z;
    } else {
        ex = cb[n * 3]; ey = cb[n * 3 + 1]; ez = cb[n * 3 + 2];
    }

    float* o0 = out + ((size_t)b << 24) + (size_t)ql * 4;           // b*16*NK + r
    float* o1 = out + OUT0_TOTAL + ((size_t)(b * 8) << 20) + (size_t)ql * 4;

    if (PREP) {
        // ---- single-line gather per neighbor: coords + features together ----
        v4f qc[4], fa[4], fbv[4];
        #pragma unroll
        for (int k = 0; k < 4; k++) {
            const v4f* rp = rec + (((size_t)(b << 16) + id[k]) << 2);
            qc[k]  = rp[0];    // x,y,z,_
            fa[k]  = rp[1];    // f0..f3
            fbv[k] = rp[2];    // f4..f7
        }
        // nf -> out0 channels 0..7 (transpose k-major -> channel-major)
        #pragma unroll
        for (int c = 0; c < 4; c++) {
            v4f vlo = {fa[0][c], fa[1][c], fa[2][c], fa[3][c]};
            v4f vhi = {fbv[0][c], fbv[1][c], fbv[2][c], fbv[3][c]};
            __builtin_nontemporal_store(vlo, (v4f*)(o0 + (size_t)c * NK));
            __builtin_nontemporal_store(vhi, (v4f*)(o0 + (size_t)(4 + c) * NK));
        }
        // y channels -> out0 channels 8..15 and out1
        float acc[8][4];
        #pragma unroll
        for (int k = 0; k < 4; k++) {
            float rx = ex - qc[k].x, ry = ey - qc[k].y, rz = ez - qc[k].z;
            float dist = sqrtf(rx * rx + ry * ry + rz * rz);
            float rf[10] = {dist, rx, ry, rz, ex, ey, ez, qc[k].x, qc[k].y, qc[k].z};
            #pragma unroll
            for (int o = 0; o < 8; o++) {
                float y = bb[o];
                #pragma unroll
                for (int c = 0; c < 10; c++) y = fmaf(w[o * 10 + c], rf[c], y);
                acc[o][k] = fmaxf(y, SLOPE * y);   // LeakyReLU(0.2)
            }
        }
        #pragma unroll
        for (int o = 0; o < 8; o++) {
            v4f v = {acc[o][0], acc[o][1], acc[o][2], acc[o][3]};
            __builtin_nontemporal_store(v, (v4f*)(o0 + (size_t)(8 + o) * NK));
            __builtin_nontemporal_store(v, (v4f*)(o1 + (size_t)o * NK));
        }
    } else {
        // ---- fallback: raw gathers ----
        const float* fb = features + (size_t)b * 8 * Nn;
        #pragma unroll
        for (int d = 0; d < 8; d++) {
            v4f v = {fb[(size_t)d * Nn + id[0]], fb[(size_t)d * Nn + id[1]],
                     fb[(size_t)d * Nn + id[2]], fb[(size_t)d * Nn + id[3]]};
            __builtin_nontemporal_store(v, (v4f*)(o0 + (size_t)d * NK));
        }
        float acc[8][4];
        #pragma unroll
        for (int k = 0; k < 4; k++) {
            float nx = cb[id[k] * 3], ny = cb[id[k] * 3 + 1], nz = cb[id[k] * 3 + 2];
            float rx = ex - nx, ry = ey - ny, rz = ez - nz;
            float dist = sqrtf(rx * rx + ry * ry + rz * rz);
            float rf[10] = {dist, rx, ry, rz, ex, ey, ez, nx, ny, nz};
            #pragma unroll
            for (int o = 0; o < 8; o++) {
                float y = bb[o];
                #pragma unroll
                for (int c = 0; c < 10; c++) y = fmaf(w[o * 10 + c], rf[c], y);
                acc[o][k] = fmaxf(y, SLOPE * y);
            }
        }
        #pragma unroll
        for (int o = 0; o < 8; o++) {
            v4f v = {acc[o][0], acc[o][1], acc[o][2], acc[o][3]};
            __builtin_nontemporal_store(v, (v4f*)(o0 + (size_t)(8 + o) * NK));
            __builtin_nontemporal_store(v, (v4f*)(o1 + (size_t)o * NK));
        }
    }
}

extern "C" void kernel_launch(void* const* d_in, const int* in_sizes, int n_in,
                              void* d_out, int out_size, void* d_ws, size_t ws_size,
                              hipStream_t stream) {
    const float* coords   = (const float*)d_in[0];   // (4,65536,3)
    const float* features = (const float*)d_in[1];   // (4,8,65536,1)
    const int*   nbr      = (const int*)d_in[2];     // (4,65536,16)
    const float* conv_w   = (const float*)d_in[3];   // (8,10)
    const float* conv_b   = (const float*)d_in[4];   // (8,)
    const float* gamma    = (const float*)d_in[5];   // (8,)
    const float* beta     = (const float*)d_in[6];   // (8,)
    float* out = (float*)d_out;
    const v4i* nbr4 = (const v4i*)nbr;

    float* stats = (float*)d_ws;
    const size_t CPAD_OFF = 1024;
    const size_t CPAD_BYTES = (size_t)Bn * Nn * 4 * sizeof(float);    // 4 MB
    const size_t REC_OFF = CPAD_OFF + CPAD_BYTES;
    const size_t REC_BYTES = (size_t)Bn * Nn * 16 * sizeof(float);    // 16 MB
    const size_t NEED = REC_OFF + REC_BYTES;
    v4f* cpad = (v4f*)((char*)d_ws + CPAD_OFF);
    v4f* rec  = (v4f*)((char*)d_ws + REC_OFF);

    const bool prep = (ws_size >= NEED);
    if (prep) {
        prep_kernel<<<(Bn * Nn) / 256, 256, 0, stream>>>(coords, features, stats, cpad, rec);
        reduce_kernel<true><<<1024, 256, 0, stream>>>(nbr4, cpad, coords, conv_w, conv_b, stats);
    } else {
        init_kernel<<<1, 64, 0, stream>>>(stats);
        reduce_kernel<false><<<1024, 256, 0, stream>>>(nbr4, cpad, coords, conv_w, conv_b, stats);
    }
    finalize_kernel<<<1, 128, 0, stream>>>(conv_w, conv_b, gamma, beta, stats);
    if (prep)
        output_kernel<true><<<4096, 256, 0, stream>>>(nbr4, cpad, coords, rec, features, stats, out);
    else
        output_kernel<false><<<4096, 256, 0, stream>>>(nbr4, cpad, coords, rec, features, stats, out);
}

// Round 4
// 487.591 us; speedup vs baseline: 1.0256x; 1.0256x over previous
//
#include <hip/hip_runtime.h>
#include <cstdint>
#include <cstddef>

typedef float v4f __attribute__((ext_vector_type(4)));
typedef int   v4i __attribute__((ext_vector_type(4)));

// Problem constants (from reference): B=4, N=65536, K=16, D=8, OUT=8
namespace {
constexpr int Bn = 4;
constexpr int Nn = 65536;
constexpr int Kn = 16;
constexpr int NK = Nn * Kn;          // 1<<20
constexpr int TOTAL = Bn * NK;       // 1<<22 = 4,194,304
constexpr int QPB = NK / 4;          // quads per batch = 262144 = 1<<18
constexpr float COUNT_F = 4194304.0f;
constexpr float EPS = 1e-6f;
constexpr float SLOPE = 0.2f;
// out0 = (B,16,N,K) then out1 = (B,8,N,K), concatenated flat
constexpr long long OUT0_TOTAL = (long long)Bn * 16 * NK;  // 67,108,864
}

// Force a uniform value toward SGPR allocation (frees VGPRs -> occupancy).
__device__ __forceinline__ float uni(float x) {
    return __int_as_float(__builtin_amdgcn_readfirstlane(__float_as_int(x)));
}

// ws layout (bytes):
//   [0, 416)            : stats — [0..7]=sum, [8..15]=sumsq
//   [1024, 1024+4MB)    : cpad  — coords padded to float4, B*N entries (1 MB/batch)
//   [1024+4MB, +8MB)    : tf    — features transposed to (B,N,8), 2x float4 (2 MB/batch)
// Per-batch gather set = 3 MB -> resident in a 4 MB XCD L2 (2 XCDs per batch).

// ---------------- prep: zero stats, pad coords, transpose features ----------------
__global__ __launch_bounds__(256) void prep_kernel(
    const float* __restrict__ coords,     // (B,N,3)
    const float* __restrict__ features,   // (B,8,N)
    float* __restrict__ stats,
    v4f* __restrict__ cpad,               // B*N
    v4f* __restrict__ tf)                 // B*N*2
{
    if (blockIdx.x == 0 && threadIdx.x < 16) stats[threadIdx.x] = 0.0f;
    int t = blockIdx.x * blockDim.x + threadIdx.x;   // 0 .. B*N-1
    if (t >= Bn * Nn) return;
    int b = t >> 16;             // N = 65536
    int n = t & (Nn - 1);
    const float* c = coords + (size_t)t * 3;
    v4f cv = {c[0], c[1], c[2], 0.0f};
    cpad[t] = cv;
    const float* fb = features + (size_t)b * 8 * Nn + n;
    v4f lo = {fb[0 * Nn], fb[1 * Nn], fb[2 * Nn], fb[3 * Nn]};
    v4f hi = {fb[4 * Nn], fb[5 * Nn], fb[6 * Nn], fb[7 * Nn]};
    tf[2 * t]     = lo;
    tf[2 * t + 1] = hi;
}

// ---------------- fallback stats init (no-prep path) ----------------
__global__ void init_kernel(float* __restrict__ stats) {
    if (threadIdx.x < 16) stats[threadIdx.x] = 0.0f;
}

// ---------------- pass 1: per-channel sum & sumsq of pre-BN y ----------------
// k-quad per thread; XCD-pinned batch mapping: blocks with ((blockIdx&7)>>1)==b
// only touch batch b's 1 MB cpad -> stays resident in that XCD's 4 MB L2.
template <bool PREP>
__global__ __launch_bounds__(256) void reduce_kernel(
    const v4i* __restrict__ nbr4,         // (B,N,K/4) int4
    const v4f* __restrict__ cpad,
    const float* __restrict__ coords,
    const float* __restrict__ conv_w,     // (8,10)
    const float* __restrict__ conv_b,     // (8,)
    float* __restrict__ stats)
{
    float w[80];
    #pragma unroll
    for (int i = 0; i < 80; i++) w[i] = uni(conv_w[i]);   // uniform -> SGPR
    float bb[8];
    #pragma unroll
    for (int i = 0; i < 8; i++) bb[i] = uni(conv_b[i]);

    float s[8], sq[8];
    #pragma unroll
    for (int i = 0; i < 8; i++) { s[i] = 0.0f; sq[i] = 0.0f; }

    int xcd = blockIdx.x & 7;
    int b   = xcd >> 1;                                  // 2 XCDs per batch
    int wb  = ((blockIdx.x >> 3) << 1) | (xcd & 1);      // 0 .. gridDim/4-1
    int stride = (gridDim.x >> 2) * blockDim.x;          // threads per batch
    const float* cb = coords + (size_t)b * Nn * 3;

    for (int ql = wb * blockDim.x + threadIdx.x; ql < QPB; ql += stride) {
        v4i idx = __builtin_nontemporal_load(&nbr4[(b << 18) + ql]);
        int id[4] = {idx.x, idx.y, idx.z, idx.w};
        int n = ql >> 2;
        float ex, ey, ez;
        if (PREP) {
            v4f e = cpad[(b << 16) + n];
            ex = e.x; ey = e.y; ez = e.z;
        } else {
            ex = cb[n * 3]; ey = cb[n * 3 + 1]; ez = cb[n * 3 + 2];
        }
        #pragma unroll
        for (int k = 0; k < 4; k++) {
            float nx, ny, nz;
            if (PREP) {
                v4f q = cpad[(b << 16) + id[k]];
                nx = q.x; ny = q.y; nz = q.z;
            } else {
                nx = cb[id[k] * 3]; ny = cb[id[k] * 3 + 1]; nz = cb[id[k] * 3 + 2];
            }
            float rx = ex - nx, ry = ey - ny, rz = ez - nz;
            float dist = sqrtf(rx * rx + ry * ry + rz * rz);
            float rf[10] = {dist, rx, ry, rz, ex, ey, ez, nx, ny, nz};
            #pragma unroll
            for (int o = 0; o < 8; o++) {
                float y = bb[o];
                #pragma unroll
                for (int c = 0; c < 10; c++) y = fmaf(w[o * 10 + c], rf[c], y);
                s[o] += y;
                sq[o] = fmaf(y, y, sq[o]);
            }
        }
    }

    // wave-64 butterfly reduction of 16 values
    #pragma unroll
    for (int i = 0; i < 8; i++) {
        #pragma unroll
        for (int off = 32; off > 0; off >>= 1) {
            s[i]  += __shfl_xor(s[i], off, 64);
            sq[i] += __shfl_xor(sq[i], off, 64);
        }
    }
    __shared__ float ls[4][16];
    int lane = threadIdx.x & 63;
    int wv = threadIdx.x >> 6;
    if (lane == 0) {
        #pragma unroll
        for (int i = 0; i < 8; i++) { ls[wv][i] = s[i]; ls[wv][8 + i] = sq[i]; }
    }
    __syncthreads();
    if (threadIdx.x < 16) {
        float a = ls[0][threadIdx.x] + ls[1][threadIdx.x]
                + ls[2][threadIdx.x] + ls[3][threadIdx.x];
        atomicAdd(&stats[threadIdx.x], a);
    }
}

// ---------------- pass 2: fold BN inline, recompute y, gather nf, write outputs ----------------
// One k-quad per thread (grid exactly covers B*N*K/4). BN folding (former
// finalize_kernel) is computed per-thread from raw sums: 88 uniform FLOPs, free.
// All 24 output channels are float4 nontemporal stores.
template <bool PREP>
__global__ __launch_bounds__(256) void output_kernel(
    const v4i* __restrict__ nbr4,
    const v4f* __restrict__ cpad,
    const float* __restrict__ coords,
    const v4f* __restrict__ tf,           // (B,N,8) as 2x float4
    const float* __restrict__ features,   // raw (B,8,N) for fallback
    const float* __restrict__ stats,      // raw sums: [0..7]=sum, [8..15]=sumsq
    const float* __restrict__ conv_w,
    const float* __restrict__ conv_b,
    const float* __restrict__ gamma,
    const float* __restrict__ beta,
    float* __restrict__ out)
{
    // ---- inline BN fold (uniform, scalarized) ----
    float w[80], bb[8];
    #pragma unroll
    for (int o = 0; o < 8; o++) {
        float mean = stats[o] * (1.0f / COUNT_F);
        float var = stats[8 + o] * (1.0f / COUNT_F) - mean * mean;
        var = fmaxf(var, 0.0f);
        float scale = gamma[o] * rsqrtf(var + EPS);
        bb[o] = uni((conv_b[o] - mean) * scale + beta[o]);
        #pragma unroll
        for (int c = 0; c < 10; c++) w[o * 10 + c] = uni(conv_w[o * 10 + c] * scale);
    }

    int xcd = blockIdx.x & 7;
    int b   = xcd >> 1;                                  // 2 XCDs per batch
    int wb  = ((blockIdx.x >> 3) << 1) | (xcd & 1);      // 0..1023
    int ql  = wb * blockDim.x + threadIdx.x;             // 0..262143 (quad id in batch)
    int n   = ql >> 2;

    v4i idx = __builtin_nontemporal_load(&nbr4[(b << 18) + ql]);
    int id[4] = {idx.x, idx.y, idx.z, idx.w};

    const float* cb = coords + (size_t)b * Nn * 3;
    float ex, ey, ez;
    if (PREP) {
        v4f e = cpad[(b << 16) + n];
        ex = e.x; ey = e.y; ez = e.z;
    } else {
        ex = cb[n * 3]; ey = cb[n * 3 + 1]; ez = cb[n * 3 + 2];
    }

    float* o0 = out + ((size_t)b << 24) + (size_t)ql * 4;           // b*16*NK + r
    float* o1 = out + OUT0_TOTAL + ((size_t)(b * 8) << 20) + (size_t)ql * 4;

    if (PREP) {
        // ---- gathers: issue all loads up front (cpad + tf) ----
        v4f qc[4], lo[4], hi[4];
        #pragma unroll
        for (int k = 0; k < 4; k++) {
            qc[k] = cpad[(b << 16) + id[k]];
            lo[k] = tf[2 * ((b << 16) + id[k])];
            hi[k] = tf[2 * ((b << 16) + id[k]) + 1];
        }
        // nf -> out0 channels 0..7 (transpose k-major -> channel-major)
        #pragma unroll
        for (int c = 0; c < 4; c++) {
            v4f vlo = {lo[0][c], lo[1][c], lo[2][c], lo[3][c]};
            v4f vhi = {hi[0][c], hi[1][c], hi[2][c], hi[3][c]};
            __builtin_nontemporal_store(vlo, (v4f*)(o0 + (size_t)c * NK));
            __builtin_nontemporal_store(vhi, (v4f*)(o0 + (size_t)(4 + c) * NK));
        }
        // y channels -> out0 channels 8..15 and out1
        float acc[8][4];
        #pragma unroll
        for (int k = 0; k < 4; k++) {
            float rx = ex - qc[k].x, ry = ey - qc[k].y, rz = ez - qc[k].z;
            float dist = sqrtf(rx * rx + ry * ry + rz * rz);
            float rf[10] = {dist, rx, ry, rz, ex, ey, ez, qc[k].x, qc[k].y, qc[k].z};
            #pragma unroll
            for (int o = 0; o < 8; o++) {
                float y = bb[o];
                #pragma unroll
                for (int c = 0; c < 10; c++) y = fmaf(w[o * 10 + c], rf[c], y);
                acc[o][k] = fmaxf(y, SLOPE * y);   // LeakyReLU(0.2)
            }
        }
        #pragma unroll
        for (int o = 0; o < 8; o++) {
            v4f v = {acc[o][0], acc[o][1], acc[o][2], acc[o][3]};
            __builtin_nontemporal_store(v, (v4f*)(o0 + (size_t)(8 + o) * NK));
            __builtin_nontemporal_store(v, (v4f*)(o1 + (size_t)o * NK));
        }
    } else {
        // ---- fallback: raw gathers ----
        const float* fb = features + (size_t)b * 8 * Nn;
        #pragma unroll
        for (int d = 0; d < 8; d++) {
            v4f v = {fb[(size_t)d * Nn + id[0]], fb[(size_t)d * Nn + id[1]],
                     fb[(size_t)d * Nn + id[2]], fb[(size_t)d * Nn + id[3]]};
            __builtin_nontemporal_store(v, (v4f*)(o0 + (size_t)d * NK));
        }
        float acc[8][4];
        #pragma unroll
        for (int k = 0; k < 4; k++) {
            float nx = cb[id[k] * 3], ny = cb[id[k] * 3 + 1], nz = cb[id[k] * 3 + 2];
            float rx = ex - nx, ry = ey - ny, rz = ez - nz;
            float dist = sqrtf(rx * rx + ry * ry + rz * rz);
            float rf[10] = {dist, rx, ry, rz, ex, ey, ez, nx, ny, nz};
            #pragma unroll
            for (int o = 0; o < 8; o++) {
                float y = bb[o];
                #pragma unroll
                for (int c = 0; c < 10; c++) y = fmaf(w[o * 10 + c], rf[c], y);
                acc[o][k] = fmaxf(y, SLOPE * y);
            }
        }
        #pragma unroll
        for (int o = 0; o < 8; o++) {
            v4f v = {acc[o][0], acc[o][1], acc[o][2], acc[o][3]};
            __builtin_nontemporal_store(v, (v4f*)(o0 + (size_t)(8 + o) * NK));
            __builtin_nontemporal_store(v, (v4f*)(o1 + (size_t)o * NK));
        }
    }
}

extern "C" void kernel_launch(void* const* d_in, const int* in_sizes, int n_in,
                              void* d_out, int out_size, void* d_ws, size_t ws_size,
                              hipStream_t stream) {
    const float* coords   = (const float*)d_in[0];   // (4,65536,3)
    const float* features = (const float*)d_in[1];   // (4,8,65536,1)
    const int*   nbr      = (const int*)d_in[2];     // (4,65536,16)
    const float* conv_w   = (const float*)d_in[3];   // (8,10)
    const float* conv_b   = (const float*)d_in[4];   // (8,)
    const float* gamma    = (const float*)d_in[5];   // (8,)
    const float* beta     = (const float*)d_in[6];   // (8,)
    float* out = (float*)d_out;
    const v4i* nbr4 = (const v4i*)nbr;

    float* stats = (float*)d_ws;
    const size_t CPAD_OFF = 1024;
    const size_t CPAD_BYTES = (size_t)Bn * Nn * 4 * sizeof(float);   // 4 MB
    const size_t TF_OFF = CPAD_OFF + CPAD_BYTES;
    const size_t TF_BYTES = (size_t)Bn * Nn * 8 * sizeof(float);     // 8 MB
    const size_t NEED = TF_OFF + TF_BYTES;
    v4f* cpad = (v4f*)((char*)d_ws + CPAD_OFF);
    v4f* tf   = (v4f*)((char*)d_ws + TF_OFF);

    const bool prep = (ws_size >= NEED);
    if (prep) {
        prep_kernel<<<(Bn * Nn) / 256, 256, 0, stream>>>(coords, features, stats, cpad, tf);
        reduce_kernel<true><<<2048, 256, 0, stream>>>(nbr4, cpad, coords, conv_w, conv_b, stats);
        output_kernel<true><<<4096, 256, 0, stream>>>(nbr4, cpad, coords, tf, features, stats,
                                                      conv_w, conv_b, gamma, beta, out);
    } else {
        init_kernel<<<1, 64, 0, stream>>>(stats);
        reduce_kernel<false><<<2048, 256, 0, stream>>>(nbr4, cpad, coords, conv_w, conv_b, stats);
        output_kernel<false><<<4096, 256, 0, stream>>>(nbr4, cpad, coords, tf, features, stats,
                                                       conv_w, conv_b, gamma, beta, out);
    }
}

// Round 5
// 477.873 us; speedup vs baseline: 1.0464x; 1.0203x over previous
//
#include <hip/hip_runtime.h>
#include <cstdint>
#include <cstddef>

typedef float    v4f __attribute__((ext_vector_type(4)));
typedef int      v4i __attribute__((ext_vector_type(4)));
typedef _Float16 h8  __attribute__((ext_vector_type(8)));

// Problem constants (from reference): B=4, N=65536, K=16, D=8, OUT=8
namespace {
constexpr int Bn = 4;
constexpr int Nn = 65536;
constexpr int Kn = 16;
constexpr int NK = Nn * Kn;          // 1<<20
constexpr int TOTAL = Bn * NK;       // 1<<22 = 4,194,304
constexpr int QPB = NK / 4;          // quads per batch = 262144 = 1<<18
constexpr float COUNT_F = 4194304.0f;
constexpr float EPS = 1e-6f;
constexpr float SLOPE = 0.2f;
// out0 = (B,16,N,K) then out1 = (B,8,N,K), concatenated flat
constexpr long long OUT0_TOTAL = (long long)Bn * 16 * NK;  // 67,108,864
}

// ws layout (bytes):
//   [0, 416)            : stats — [0..7]=sum, [8..15]=sumsq, [16..95]=fused W, [96..103]=fused b
//   [1024, 1024+4MB)    : cpad  — coords padded to float4, B*N (1 MB/batch)
//   [1024+4MB, +2MB)    : tfh   — features as 8x fp16 per point, 16B (0.5 MB/batch)
// Per-batch gather set = 1.5 MB -> comfortably resident in a 4 MB XCD L2.

// ---------------- prep: zero stats, pad coords, fp16-transpose features ----------------
__global__ __launch_bounds__(256) void prep_kernel(
    const float* __restrict__ coords,     // (B,N,3)
    const float* __restrict__ features,   // (B,8,N)
    float* __restrict__ stats,
    v4f* __restrict__ cpad,               // B*N
    v4f* __restrict__ tfh)                // B*N, 16B of 8x fp16 per point
{
    if (blockIdx.x == 0 && threadIdx.x < 16) stats[threadIdx.x] = 0.0f;
    int t = blockIdx.x * blockDim.x + threadIdx.x;   // 0 .. B*N-1
    if (t >= Bn * Nn) return;
    int b = t >> 16;             // N = 65536
    int n = t & (Nn - 1);
    const float* c = coords + (size_t)t * 3;
    v4f cv = {c[0], c[1], c[2], 0.0f};
    __builtin_nontemporal_store(cv, &cpad[t]);
    const float* fb = features + (size_t)b * 8 * Nn + n;
    h8 hv;
    #pragma unroll
    for (int d = 0; d < 8; d++) hv[d] = (_Float16)fb[(size_t)d * Nn];
    __builtin_nontemporal_store(*(const v4f*)&hv, &tfh[t]);
}

// ---------------- fallback stats init (no-prep path) ----------------
__global__ void init_kernel(float* __restrict__ stats) {
    if (threadIdx.x < 16) stats[threadIdx.x] = 0.0f;
}

// ---------------- pass 1: per-channel sum & sumsq of pre-BN y ----------------
// k-quad per thread; XCD-pinned batch mapping: blocks with ((blockIdx&7)>>1)==b
// only touch batch b's 1 MB cpad -> stays resident in that XCD's 4 MB L2.
template <bool PREP>
__global__ __launch_bounds__(256) void reduce_kernel(
    const v4i* __restrict__ nbr4,         // (B,N,K/4) int4
    const v4f* __restrict__ cpad,
    const float* __restrict__ coords,
    const float* __restrict__ conv_w,     // (8,10)
    const float* __restrict__ conv_b,     // (8,)
    float* __restrict__ stats)
{
    float w[80];
    #pragma unroll
    for (int i = 0; i < 80; i++) w[i] = conv_w[i];   // uniform addr -> s_load
    float bb[8];
    #pragma unroll
    for (int i = 0; i < 8; i++) bb[i] = conv_b[i];

    float s[8], sq[8];
    #pragma unroll
    for (int i = 0; i < 8; i++) { s[i] = 0.0f; sq[i] = 0.0f; }

    int xcd = blockIdx.x & 7;
    int b   = xcd >> 1;                                  // 2 XCDs per batch
    int wb  = ((blockIdx.x >> 3) << 1) | (xcd & 1);      // 0 .. gridDim/4-1
    int stride = (gridDim.x >> 2) * blockDim.x;          // threads per batch
    const float* cb = coords + (size_t)b * Nn * 3;

    for (int ql = wb * blockDim.x + threadIdx.x; ql < QPB; ql += stride) {
        v4i idx = __builtin_nontemporal_load(&nbr4[(b << 18) + ql]);
        int id[4] = {idx.x, idx.y, idx.z, idx.w};
        int n = ql >> 2;
        float ex, ey, ez;
        if (PREP) {
            v4f e = cpad[(b << 16) + n];
            ex = e.x; ey = e.y; ez = e.z;
        } else {
            ex = cb[n * 3]; ey = cb[n * 3 + 1]; ez = cb[n * 3 + 2];
        }
        #pragma unroll
        for (int k = 0; k < 4; k++) {
            float nx, ny, nz;
            if (PREP) {
                v4f q = cpad[(b << 16) + id[k]];
                nx = q.x; ny = q.y; nz = q.z;
            } else {
                nx = cb[id[k] * 3]; ny = cb[id[k] * 3 + 1]; nz = cb[id[k] * 3 + 2];
            }
            float rx = ex - nx, ry = ey - ny, rz = ez - nz;
            float dist = sqrtf(rx * rx + ry * ry + rz * rz);
            float rf[10] = {dist, rx, ry, rz, ex, ey, ez, nx, ny, nz};
            #pragma unroll
            for (int o = 0; o < 8; o++) {
                float y = bb[o];
                #pragma unroll
                for (int c = 0; c < 10; c++) y = fmaf(w[o * 10 + c], rf[c], y);
                s[o] += y;
                sq[o] = fmaf(y, y, sq[o]);
            }
        }
    }

    // wave-64 butterfly reduction of 16 values
    #pragma unroll
    for (int i = 0; i < 8; i++) {
        #pragma unroll
        for (int off = 32; off > 0; off >>= 1) {
            s[i]  += __shfl_xor(s[i], off, 64);
            sq[i] += __shfl_xor(sq[i], off, 64);
        }
    }
    __shared__ float ls[4][16];
    int lane = threadIdx.x & 63;
    int wv = threadIdx.x >> 6;
    if (lane == 0) {
        #pragma unroll
        for (int i = 0; i < 8; i++) { ls[wv][i] = s[i]; ls[wv][8 + i] = sq[i]; }
    }
    __syncthreads();
    if (threadIdx.x < 16) {
        float a = ls[0][threadIdx.x] + ls[1][threadIdx.x]
                + ls[2][threadIdx.x] + ls[3][threadIdx.x];
        atomicAdd(&stats[threadIdx.x], a);
    }
}

// ---------------- finalize: fold BN into conv weights (kept separate ON PURPOSE:
// output_kernel s_loads the fused coeffs -> SGPR file, zero VGPR pressure) ----------------
__global__ void finalize_kernel(
    const float* __restrict__ conv_w,
    const float* __restrict__ conv_b,
    const float* __restrict__ gamma,
    const float* __restrict__ beta,
    float* __restrict__ stats)
{
    int j = threadIdx.x;
    if (j >= 88) return;
    int o = (j < 80) ? (j / 10) : (j - 80);
    float mean = stats[o] * (1.0f / COUNT_F);
    float var = stats[8 + o] * (1.0f / COUNT_F) - mean * mean;
    var = fmaxf(var, 0.0f);
    float scale = gamma[o] * rsqrtf(var + EPS);
    if (j < 80) stats[16 + j] = conv_w[j] * scale;                    // fused W
    else        stats[96 + o] = (conv_b[o] - mean) * scale + beta[o]; // fused b
}

// ---------------- pass 2: recompute y (fused BN), gather nf, write outputs ----------------
// One k-quad per thread. PHASED gathers (tfh -> nf stores, then cpad -> y stores)
// keep peak live registers low; launch_bounds(256,4) targets 4 blocks/CU.
template <bool PREP>
__global__ __launch_bounds__(256, 4) void output_kernel(
    const v4i* __restrict__ nbr4,
    const v4f* __restrict__ cpad,
    const float* __restrict__ coords,
    const v4f* __restrict__ tfh,          // 8x fp16 per point
    const float* __restrict__ features,   // raw (B,8,N) for fallback
    const float* __restrict__ stats,
    float* __restrict__ out)
{
    float w[80];
    #pragma unroll
    for (int i = 0; i < 80; i++) w[i] = stats[16 + i];  // uniform addr -> s_load (SGPR)
    float bb[8];
    #pragma unroll
    for (int i = 0; i < 8; i++) bb[i] = stats[96 + i];

    int xcd = blockIdx.x & 7;
    int b   = xcd >> 1;                                  // 2 XCDs per batch
    int wb  = ((blockIdx.x >> 3) << 1) | (xcd & 1);      // 0..1023
    int ql  = wb * blockDim.x + threadIdx.x;             // 0..262143 (quad id in batch)
    int n   = ql >> 2;

    v4i idx = __builtin_nontemporal_load(&nbr4[(b << 18) + ql]);
    int id[4] = {idx.x, idx.y, idx.z, idx.w};

    const float* cb = coords + (size_t)b * Nn * 3;

    float* o0 = out + ((size_t)b << 24) + (size_t)ql * 4;           // b*16*NK + r
    float* o1 = out + OUT0_TOTAL + ((size_t)(b * 8) << 20) + (size_t)ql * 4;

    if (PREP) {
        // ---- phase A: fp16 feature gathers (1 dwordx4 per neighbor) -> nf stores ----
        {
            h8 hf[4];
            #pragma unroll
            for (int k = 0; k < 4; k++) {
                v4f t = tfh[(b << 16) + id[k]];
                hf[k] = *(const h8*)&t;
            }
            #pragma unroll
            for (int c = 0; c < 8; c++) {
                v4f v = {(float)hf[0][c], (float)hf[1][c], (float)hf[2][c], (float)hf[3][c]};
                __builtin_nontemporal_store(v, (v4f*)(o0 + (size_t)c * NK));
            }
        }
        // ---- phase B: coord gathers -> y compute -> stores ----
        v4f e = cpad[(b << 16) + n];
        float ex = e.x, ey = e.y, ez = e.z;
        v4f qc[4];
        #pragma unroll
        for (int k = 0; k < 4; k++) qc[k] = cpad[(b << 16) + id[k]];
        float acc[8][4];
        #pragma unroll
        for (int k = 0; k < 4; k++) {
            float rx = ex - qc[k].x, ry = ey - qc[k].y, rz = ez - qc[k].z;
            float dist = sqrtf(rx * rx + ry * ry + rz * rz);
            float rf[10] = {dist, rx, ry, rz, ex, ey, ez, qc[k].x, qc[k].y, qc[k].z};
            #pragma unroll
            for (int o = 0; o < 8; o++) {
                float y = bb[o];
                #pragma unroll
                for (int c = 0; c < 10; c++) y = fmaf(w[o * 10 + c], rf[c], y);
                acc[o][k] = fmaxf(y, SLOPE * y);   // LeakyReLU(0.2)
            }
        }
        #pragma unroll
        for (int o = 0; o < 8; o++) {
            v4f v = {acc[o][0], acc[o][1], acc[o][2], acc[o][3]};
            __builtin_nontemporal_store(v, (v4f*)(o0 + (size_t)(8 + o) * NK));
            __builtin_nontemporal_store(v, (v4f*)(o1 + (size_t)o * NK));
        }
    } else {
        // ---- fallback: raw gathers (exact fp32) ----
        const float* fb = features + (size_t)b * 8 * Nn;
        #pragma unroll
        for (int d = 0; d < 8; d++) {
            v4f v = {fb[(size_t)d * Nn + id[0]], fb[(size_t)d * Nn + id[1]],
                     fb[(size_t)d * Nn + id[2]], fb[(size_t)d * Nn + id[3]]};
            __builtin_nontemporal_store(v, (v4f*)(o0 + (size_t)d * NK));
        }
        float ex = cb[n * 3], ey = cb[n * 3 + 1], ez = cb[n * 3 + 2];
        float acc[8][4];
        #pragma unroll
        for (int k = 0; k < 4; k++) {
            float nx = cb[id[k] * 3], ny = cb[id[k] * 3 + 1], nz = cb[id[k] * 3 + 2];
            float rx = ex - nx, ry = ey - ny, rz = ez - nz;
            float dist = sqrtf(rx * rx + ry * ry + rz * rz);
            float rf[10] = {dist, rx, ry, rz, ex, ey, ez, nx, ny, nz};
            #pragma unroll
            for (int o = 0; o < 8; o++) {
                float y = bb[o];
                #pragma unroll
                for (int c = 0; c < 10; c++) y = fmaf(w[o * 10 + c], rf[c], y);
                acc[o][k] = fmaxf(y, SLOPE * y);
            }
        }
        #pragma unroll
        for (int o = 0; o < 8; o++) {
            v4f v = {acc[o][0], acc[o][1], acc[o][2], acc[o][3]};
            __builtin_nontemporal_store(v, (v4f*)(o0 + (size_t)(8 + o) * NK));
            __builtin_nontemporal_store(v, (v4f*)(o1 + (size_t)o * NK));
        }
    }
}

extern "C" void kernel_launch(void* const* d_in, const int* in_sizes, int n_in,
                              void* d_out, int out_size, void* d_ws, size_t ws_size,
                              hipStream_t stream) {
    const float* coords   = (const float*)d_in[0];   // (4,65536,3)
    const float* features = (const float*)d_in[1];   // (4,8,65536,1)
    const int*   nbr      = (const int*)d_in[2];     // (4,65536,16)
    const float* conv_w   = (const float*)d_in[3];   // (8,10)
    const float* conv_b   = (const float*)d_in[4];   // (8,)
    const float* gamma    = (const float*)d_in[5];   // (8,)
    const float* beta     = (const float*)d_in[6];   // (8,)
    float* out = (float*)d_out;
    const v4i* nbr4 = (const v4i*)nbr;

    float* stats = (float*)d_ws;
    const size_t CPAD_OFF = 1024;
    const size_t CPAD_BYTES = (size_t)Bn * Nn * 4 * sizeof(float);   // 4 MB
    const size_t TFH_OFF = CPAD_OFF + CPAD_BYTES;
    const size_t TFH_BYTES = (size_t)Bn * Nn * 16;                   // 2 MB (8x fp16)
    const size_t NEED = TFH_OFF + TFH_BYTES;
    v4f* cpad = (v4f*)((char*)d_ws + CPAD_OFF);
    v4f* tfh  = (v4f*)((char*)d_ws + TFH_OFF);

    const bool prep = (ws_size >= NEED);
    if (prep) {
        prep_kernel<<<(Bn * Nn) / 256, 256, 0, stream>>>(coords, features, stats, cpad, tfh);
        reduce_kernel<true><<<1024, 256, 0, stream>>>(nbr4, cpad, coords, conv_w, conv_b, stats);
    } else {
        init_kernel<<<1, 64, 0, stream>>>(stats);
        reduce_kernel<false><<<1024, 256, 0, stream>>>(nbr4, cpad, coords, conv_w, conv_b, stats);
    }
    finalize_kernel<<<1, 128, 0, stream>>>(conv_w, conv_b, gamma, beta, stats);
    if (prep)
        output_kernel<true><<<4096, 256, 0, stream>>>(nbr4, cpad, coords, tfh, features, stats, out);
    else
        output_kernel<false><<<4096, 256, 0, stream>>>(nbr4, cpad, coords, tfh, features, stats, out);
}